// Round 7
// baseline (257.720 us; speedup 1.0000x reference)
//
#include <hip/hip_runtime.h>
#include <math.h>

// Sum-product network over a binary tree. B=256, D=1024 leaves, K=128.
// Linear-domain carry: each level stores S[b,n,i] in (0,1] and M[b,n] with
//   y = M + log S. Per level: E = S_a*S_b, mu = rowmax(E), gemm Wn·(E/mu),
//   M' = M_a+M_b+log(mu), where Wn = softmax(w) (normalized once).
// exp only at the leaves, log only at the root. GEMM = MFMA 16x16x32 bf16
// split-precision (hi+lo, 3 MFMAs). Tail (d=16..1) fused into one kernel.

#define DD 1024
#define KK 128
#define HALF_LOG_2PI 0.9189385332046727f

typedef __attribute__((ext_vector_type(8))) short bf16x8;
typedef __attribute__((ext_vector_type(4))) float f32x4;

__device__ __forceinline__ unsigned short bf16_rn(float f) {
    unsigned u = __builtin_bit_cast(unsigned, f);
    u += 0x7fffu + ((u >> 16) & 1u);
    return (unsigned short)(u >> 16);
}
__device__ __forceinline__ float bf16f(unsigned short h) {
    unsigned u = ((unsigned)h) << 16;
    return __builtin_bit_cast(float, u);
}

// ---------- tail-W precompute: softmax(w) split bf16 planes, swizzled --------
// nodes 992..1022 (31 nodes of levels d<=16). Plane: [node][hi|lo][128][128].
__global__ __launch_bounds__(256) void w_pre_tail(
    const float* __restrict__ weights, unsigned short* __restrict__ planes)
{
    __shared__ float red[256];
    const int nl = blockIdx.x;           // 0..30
    const int t = threadIdx.x;
    const int i = t >> 1, h = t & 1;     // row, half
    const float* wg = weights + (((size_t)(992 + nl)) << 14) + (i << 7) + (h << 6);
    float ev[64];
    float ps = 0.f;
    #pragma unroll
    for (int q = 0; q < 16; ++q) {
        const float4 v = *(const float4*)(wg + 4 * q);
        ev[4 * q + 0] = __expf(v.x); ev[4 * q + 1] = __expf(v.y);
        ev[4 * q + 2] = __expf(v.z); ev[4 * q + 3] = __expf(v.w);
        ps += (ev[4 * q + 0] + ev[4 * q + 1]) + (ev[4 * q + 2] + ev[4 * q + 3]);
    }
    red[t] = ps;
    __syncthreads();
    const float rinv = 1.f / (red[2 * i] + red[2 * i + 1]);
    unsigned short* wh = planes + ((size_t)nl << 15) + (i << 7);
    unsigned short* wl = wh + 16384;
    const int sw = (i & 7) << 3;
    #pragma unroll
    for (int c = 0; c < 8; ++c) {
        bf16x8 hv, lv;
        #pragma unroll
        for (int q = 0; q < 8; ++q) {
            const float e = ev[8 * c + q] * rinv;
            const unsigned short hb = bf16_rn(e);
            hv[q] = (short)hb;
            lv[q] = (short)bf16_rn(e - bf16f(hb));
        }
        const int j0 = (h << 6) + 8 * c;
        *(bf16x8*)&wh[j0 ^ sw] = hv;
        *(bf16x8*)&wl[j0 ^ sw] = lv;
    }
}

// ---------------- big-level kernel (d>=32) ----------------------------------
template <int BT, bool LEAF>
__global__ __launch_bounds__(512, 4) void spn_level(
    const float* __restrict__ x, const float* __restrict__ mu,
    const float* __restrict__ ls, const float* __restrict__ Ein,
    const float* __restrict__ Min, const float* __restrict__ weights,
    float* __restrict__ Eout, float* __restrict__ Mout,
    int d, int woff)
{
    constexpr int NW = 8, NRT = BT / 16, WPR = NW / NRT, NCI = 8 / WPR;

    extern __shared__ char smem[];
    unsigned short* Whi = (unsigned short*)smem;   // [128][128] bf16 hi
    unsigned short* Wlo = Whi + 16384;             // [128][128] bf16 lo
    float* musig = (float*)(Wlo + 16384);          // [768] leaf constants

    const int n     = blockIdx.x;
    const int btile = blockIdx.y;
    const int t     = threadIdx.x;
    const int node  = woff + n;

    // ---- Phase 1: softmax(W) -> split planes (swizzled) ----------------------
    {
        const int i = t >> 2, h = t & 3;   // 4 threads per row, 32 elems each
        const float* wr = weights + ((size_t)node << 14) + (i << 7) + (h << 5);
        float ev[32];
        float ps = 0.f;
        #pragma unroll
        for (int q = 0; q < 8; ++q) {
            const float4 v = *(const float4*)(wr + 4 * q);
            ev[4 * q + 0] = __expf(v.x); ev[4 * q + 1] = __expf(v.y);
            ev[4 * q + 2] = __expf(v.z); ev[4 * q + 3] = __expf(v.w);
            ps += (ev[4 * q + 0] + ev[4 * q + 1]) + (ev[4 * q + 2] + ev[4 * q + 3]);
        }
        ps += __shfl_xor(ps, 1);
        ps += __shfl_xor(ps, 2);
        const float rinv = 1.f / ps;
        const int sw = (i & 7) << 3;
        unsigned short* wh = Whi + (i << 7);
        unsigned short* wl = Wlo + (i << 7);
        #pragma unroll
        for (int c = 0; c < 4; ++c) {
            bf16x8 hv, lv;
            #pragma unroll
            for (int q = 0; q < 8; ++q) {
                const float e = ev[8 * c + q] * rinv;
                const unsigned short hb = bf16_rn(e);
                hv[q] = (short)hb;
                lv[q] = (short)bf16_rn(e - bf16f(hb));
            }
            const int j0 = (h << 5) + 8 * c;
            *(bf16x8*)&wh[j0 ^ sw] = hv;
            *(bf16x8*)&wl[j0 ^ sw] = lv;
        }
    }
    if (LEAF && t < 256) {
        const int c = t >> 7, j = t & 127;
        const float lsv = ls[(size_t)(2 * n + c) * KK + j];
        musig[c * 128 + j]       = __expf(-lsv);
        musig[256 + c * 128 + j] = -lsv - HALF_LOG_2PI;
        musig[512 + c * 128 + j] = mu[(size_t)(2 * n + c) * KK + j];
    }
    __syncthreads();

    // ---- Phase 2: A-side in registers ----------------------------------------
    const int w  = t >> 6;
    const int ln = t & 63;
    const int lr = ln & 15;
    const int lk = ln >> 4;
    const int rt  = w / WPR;
    const int ci0 = (w % WPR) * NCI;
    const int brow = btile * BT + rt * 16 + lr;

    float p[32];
    float M2;
    if (LEAF) {
        const float xa = x[(size_t)brow * DD + 2 * n];
        const float xb = x[(size_t)brow * DD + 2 * n + 1];
        #pragma unroll
        for (int ks = 0; ks < 4; ++ks) {
            #pragma unroll
            for (int g = 0; g < 2; ++g) {
                const int j = ks * 32 + lk * 8 + 4 * g;
                const float4 ia = *(const float4*)&musig[j];
                const float4 ib = *(const float4*)&musig[128 + j];
                const float4 ca = *(const float4*)&musig[256 + j];
                const float4 cb = *(const float4*)&musig[384 + j];
                const float4 ma = *(const float4*)&musig[512 + j];
                const float4 mb = *(const float4*)&musig[640 + j];
                float za, zb;
                za = (xa - ma.x) * ia.x; zb = (xb - mb.x) * ib.x;
                p[ks * 8 + 4 * g + 0] = fmaf(-0.5f * za, za, ca.x) + fmaf(-0.5f * zb, zb, cb.x);
                za = (xa - ma.y) * ia.y; zb = (xb - mb.y) * ib.y;
                p[ks * 8 + 4 * g + 1] = fmaf(-0.5f * za, za, ca.y) + fmaf(-0.5f * zb, zb, cb.y);
                za = (xa - ma.z) * ia.z; zb = (xb - mb.z) * ib.z;
                p[ks * 8 + 4 * g + 2] = fmaf(-0.5f * za, za, ca.z) + fmaf(-0.5f * zb, zb, cb.z);
                za = (xa - ma.w) * ia.w; zb = (xb - mb.w) * ib.w;
                p[ks * 8 + 4 * g + 3] = fmaf(-0.5f * za, za, ca.w) + fmaf(-0.5f * zb, zb, cb.w);
            }
        }
    } else {
        const float* ra = Ein + ((size_t)brow * (2 * d) + 2 * n) * KK;
        #pragma unroll
        for (int ks = 0; ks < 4; ++ks) {
            const int j0 = ks * 32 + lk * 8;
            const float4 a0 = *(const float4*)(ra + j0);
            const float4 a1 = *(const float4*)(ra + j0 + 4);
            const float4 b0 = *(const float4*)(ra + KK + j0);
            const float4 b1 = *(const float4*)(ra + KK + j0 + 4);
            p[ks * 8 + 0] = a0.x * b0.x; p[ks * 8 + 1] = a0.y * b0.y;
            p[ks * 8 + 2] = a0.z * b0.z; p[ks * 8 + 3] = a0.w * b0.w;
            p[ks * 8 + 4] = a1.x * b1.x; p[ks * 8 + 5] = a1.y * b1.y;
            p[ks * 8 + 6] = a1.z * b1.z; p[ks * 8 + 7] = a1.w * b1.w;
        }
    }

    // row max across this lane's 32 elems, then across the 4 lanes of the row
    float m16[16];
    #pragma unroll
    for (int q = 0; q < 16; ++q) m16[q] = fmaxf(p[q], p[q + 16]);
    float m8[8];
    #pragma unroll
    for (int q = 0; q < 8; ++q) m8[q] = fmaxf(m16[q], m16[q + 8]);
    float m4a[4];
    #pragma unroll
    for (int q = 0; q < 4; ++q) m4a[q] = fmaxf(m8[q], m8[q + 4]);
    float mx = fmaxf(fmaxf(m4a[0], m4a[1]), fmaxf(m4a[2], m4a[3]));
    mx = fmaxf(mx, __shfl_xor(mx, 16));
    mx = fmaxf(mx, __shfl_xor(mx, 32));

    bf16x8 ah[4], al[4];
    if (LEAF) {
        M2 = mx;
        #pragma unroll
        for (int ks = 0; ks < 4; ++ks)
            #pragma unroll
            for (int q = 0; q < 8; ++q) {
                const float ev = __expf(p[ks * 8 + q] - mx);
                const unsigned short hb = bf16_rn(ev);
                ah[ks][q] = (short)hb;
                al[ks][q] = (short)bf16_rn(ev - bf16f(hb));
            }
    } else {
        const float mg = fmaxf(mx, 1e-30f);
        const float rinv = 1.f / mg;
        const float Ma = Min[(size_t)brow * (2 * d) + 2 * n];
        const float Mb = Min[(size_t)brow * (2 * d) + 2 * n + 1];
        M2 = Ma + Mb + __logf(mg);
        #pragma unroll
        for (int ks = 0; ks < 4; ++ks)
            #pragma unroll
            for (int q = 0; q < 8; ++q) {
                const float ev = p[ks * 8 + q] * rinv;
                const unsigned short hb = bf16_rn(ev);
                ah[ks][q] = (short)hb;
                al[ks][q] = (short)bf16_rn(ev - bf16f(hb));
            }
    }

    // ---- Phase 3: MFMA GEMM ---------------------------------------------------
    f32x4 acc[NCI];
    #pragma unroll
    for (int ci = 0; ci < NCI; ++ci) acc[ci] = (f32x4){0.f, 0.f, 0.f, 0.f};
    #pragma unroll
    for (int ci = 0; ci < NCI; ++ci) {
        const int i = (ci0 + ci) * 16 + lr;
        const int base = i * 128;
        const int sw = (i & 7) << 3;
        #pragma unroll
        for (int ks = 0; ks < 4; ++ks) {
            const int idx = base + ((ks * 32 + lk * 8) ^ sw);
            const bf16x8 bh = *(bf16x8*)&Whi[idx];
            const bf16x8 bl = *(bf16x8*)&Wlo[idx];
            acc[ci] = __builtin_amdgcn_mfma_f32_16x16x32_bf16(ah[ks], bh, acc[ci], 0, 0, 0);
            acc[ci] = __builtin_amdgcn_mfma_f32_16x16x32_bf16(ah[ks], bl, acc[ci], 0, 0, 0);
            acc[ci] = __builtin_amdgcn_mfma_f32_16x16x32_bf16(al[ks], bh, acc[ci], 0, 0, 0);
        }
    }

    // ---- Phase 4: store S (linear) + M ---------------------------------------
    // C/D layout: col = ln&15, row = (ln>>4)*4 + reg
    #pragma unroll
    for (int r = 0; r < 4; ++r) {
        const int b = btile * BT + rt * 16 + lk * 4 + r;
        #pragma unroll
        for (int ci = 0; ci < NCI; ++ci)
            Eout[((size_t)b * d + n) * KK + (ci0 + ci) * 16 + lr] = acc[ci][r];
    }
    if (ln < 16 && ci0 == 0)
        Mout[(size_t)(btile * BT + rt * 16 + ln) * d + n] = M2;
}

// ---------------- fused tail: d = 16,8,4,2,1 --------------------------------
// One block handles 4 batch rows and all tail nodes; S ping-pongs through LDS.
template <int NOUT, bool GIN, bool GOUT>
__device__ __forceinline__ void tail_level(
    const float* __restrict__ gE, const float* __restrict__ gM,
    const float* __restrict__ lE, const float* __restrict__ lM,
    float* __restrict__ oE, float* __restrict__ oM, float* __restrict__ gOut,
    const unsigned short* __restrict__ planes, int planeBase, int blk, int t)
{
    constexpr int NN    = 2 * NOUT;
    constexpr int REP   = (NOUT >= 8) ? NOUT / 8 : 1;
    constexpr int SHARE = (NOUT >= 8) ? 1 : 8 / NOUT;
    constexpr int NCI   = 8 / SHARE;
    const int w  = t >> 6;
    const int ln = t & 63;
    const int lr = ln & 15;
    const int lk = ln >> 4;
    const int row = lr & 3;
    const bool vrow = (lr < 4);
    const int node0 = (NOUT >= 8) ? w * REP : w / SHARE;
    const int ci0   = (NOUT >= 8) ? 0 : (w % SHARE) * NCI;

    #pragma unroll
    for (int rep = 0; rep < REP; ++rep) {
        const int nd = node0 + rep;
        // A: element-wise product of the two children
        float p[32];
        #pragma unroll
        for (int ks = 0; ks < 4; ++ks) {
            #pragma unroll
            for (int hf = 0; hf < 2; ++hf) {
                const int k = ks * 32 + lk * 8 + hf * 4;
                float4 ea, eb;
                if constexpr (GIN) {
                    const float* base = gE + ((size_t)(blk * 4 + row) * NN + 2 * nd) * KK + k;
                    ea = *(const float4*)base;
                    eb = *(const float4*)(base + KK);
                } else {
                    const int scj = (k >> 2) ^ ((row & 3) << 1);
                    ea = *(const float4*)&lE[(row * NN + 2 * nd) * KK + (scj << 2)];
                    eb = *(const float4*)&lE[(row * NN + 2 * nd + 1) * KK + (scj << 2)];
                }
                const int o = ks * 8 + hf * 4;
                p[o + 0] = vrow ? ea.x * eb.x : 0.f;
                p[o + 1] = vrow ? ea.y * eb.y : 0.f;
                p[o + 2] = vrow ? ea.z * eb.z : 0.f;
                p[o + 3] = vrow ? ea.w * eb.w : 0.f;
            }
        }
        float m16[16];
        #pragma unroll
        for (int q = 0; q < 16; ++q) m16[q] = fmaxf(p[q], p[q + 16]);
        float m8[8];
        #pragma unroll
        for (int q = 0; q < 8; ++q) m8[q] = fmaxf(m16[q], m16[q + 8]);
        float m4a[4];
        #pragma unroll
        for (int q = 0; q < 4; ++q) m4a[q] = fmaxf(m8[q], m8[q + 4]);
        float mx = fmaxf(fmaxf(m4a[0], m4a[1]), fmaxf(m4a[2], m4a[3]));
        mx = fmaxf(mx, __shfl_xor(mx, 16));
        mx = fmaxf(mx, __shfl_xor(mx, 32));
        const float mg = fmaxf(mx, 1e-30f);
        const float rinv = 1.f / mg;
        float Ma, Mb;
        if constexpr (GIN) {
            Ma = gM[(size_t)(blk * 4 + row) * NN + 2 * nd];
            Mb = gM[(size_t)(blk * 4 + row) * NN + 2 * nd + 1];
        } else {
            Ma = lM[row * NN + 2 * nd];
            Mb = lM[row * NN + 2 * nd + 1];
        }
        const float M2 = Ma + Mb + __logf(mg);

        bf16x8 ah[4], al[4];
        #pragma unroll
        for (int ks = 0; ks < 4; ++ks)
            #pragma unroll
            for (int q = 0; q < 8; ++q) {
                const float ev = p[ks * 8 + q] * rinv;
                const unsigned short hb = bf16_rn(ev);
                ah[ks][q] = (short)hb;
                al[ks][q] = (short)bf16_rn(ev - bf16f(hb));
            }

        f32x4 acc[NCI];
        #pragma unroll
        for (int ci = 0; ci < NCI; ++ci) acc[ci] = (f32x4){0.f, 0.f, 0.f, 0.f};
        #pragma unroll
        for (int ci = 0; ci < NCI; ++ci) {
            const int wrow = (ci0 + ci) * 16 + lr;
            const int swr = (wrow & 7) << 3;
            const unsigned short* ph = planes + (((size_t)(planeBase + nd)) << 15) + wrow * KK;
            #pragma unroll
            for (int ks = 0; ks < 4; ++ks) {
                const int k = (ks * 32 + lk * 8) ^ swr;
                const bf16x8 bh = *(const bf16x8*)&ph[k];
                const bf16x8 bl = *(const bf16x8*)&ph[16384 + k];
                acc[ci] = __builtin_amdgcn_mfma_f32_16x16x32_bf16(ah[ks], bh, acc[ci], 0, 0, 0);
                acc[ci] = __builtin_amdgcn_mfma_f32_16x16x32_bf16(ah[ks], bl, acc[ci], 0, 0, 0);
                acc[ci] = __builtin_amdgcn_mfma_f32_16x16x32_bf16(al[ks], bh, acc[ci], 0, 0, 0);
            }
        }

        if constexpr (GOUT) {
            float mr[4];
            #pragma unroll
            for (int r = 0; r < 4; ++r) mr[r] = __shfl(M2, r);
            if (lk == 0) {
                #pragma unroll
                for (int r = 0; r < 4; ++r)
                    #pragma unroll
                    for (int ci = 0; ci < NCI; ++ci)
                        gOut[(size_t)(blk * 4 + r) * KK + (ci0 + ci) * 16 + lr] =
                            mr[r] + __logf(acc[ci][r]);
            }
        } else {
            if (lk == 0) {
                #pragma unroll
                for (int r = 0; r < 4; ++r) {
                    #pragma unroll
                    for (int ci = 0; ci < NCI; ++ci) {
                        const int icol = (ci0 + ci) * 16 + lr;
                        const int scj = (icol >> 2) ^ ((r & 3) << 1);
                        oE[(r * NOUT + nd) * KK + (scj << 2) + (icol & 3)] = acc[ci][r];
                    }
                }
            }
            if (ln < 4 && ci0 == 0) oM[ln * NOUT + nd] = M2;
        }
    }
}

__global__ __launch_bounds__(512, 4) void spn_tail(
    const float* __restrict__ E32, const float* __restrict__ M32,
    const unsigned short* __restrict__ planes, float* __restrict__ out)
{
    __shared__ float SA[4 * 16 * KK];   // 32 KB
    __shared__ float SB[4 * 8 * KK];    // 16 KB
    __shared__ float MA[4 * 16];
    __shared__ float MB2[4 * 8];
    const int blk = blockIdx.x;
    const int t   = threadIdx.x;
    tail_level<16, true,  false>(E32, M32, nullptr, nullptr, SA, MA, nullptr, planes, 0,  blk, t);
    __syncthreads();
    tail_level<8,  false, false>(nullptr, nullptr, SA, MA, SB, MB2, nullptr, planes, 16, blk, t);
    __syncthreads();
    tail_level<4,  false, false>(nullptr, nullptr, SB, MB2, SA, MA, nullptr, planes, 24, blk, t);
    __syncthreads();
    tail_level<2,  false, false>(nullptr, nullptr, SA, MA, SB, MB2, nullptr, planes, 28, blk, t);
    __syncthreads();
    tail_level<1,  false, true >(nullptr, nullptr, SB, MB2, nullptr, nullptr, out, planes, 30, blk, t);
}

extern "C" void kernel_launch(void* const* d_in, const int* in_sizes, int n_in,
                              void* d_out, int out_size, void* d_ws, size_t ws_size,
                              hipStream_t stream) {
    const float* x  = (const float*)d_in[0];
    const float* mu = (const float*)d_in[1];
    const float* ls = (const float*)d_in[2];
    const float* w  = (const float*)d_in[3];
    float* out  = (float*)d_out;
    float* buf0 = (float*)d_ws;                        // 67.1 MB (E, big levels)
    float* buf1 = buf0 + (size_t)256 * 512 * KK;       // 33.6 MB
    float* M0   = buf1 + (size_t)256 * 256 * KK;       // [256][512]
    float* M1   = M0 + 256 * 512;                      // [256][256]
    unsigned short* planes = (unsigned short*)(M1 + 256 * 256);   // 31*64 KB

    const int shA = 65536 + 3072;   // W planes + musig

    (void)hipFuncSetAttribute((const void*)spn_level<128, true>,
                              hipFuncAttributeMaxDynamicSharedMemorySize, shA);
    (void)hipFuncSetAttribute((const void*)spn_level<128, false>,
                              hipFuncAttributeMaxDynamicSharedMemorySize, shA);
    (void)hipFuncSetAttribute((const void*)spn_level<32, false>,
                              hipFuncAttributeMaxDynamicSharedMemorySize, shA);

    w_pre_tail<<<dim3(31), dim3(256), 0, stream>>>(w, planes);

    spn_level<128, true><<<dim3(512, 2), dim3(512), shA, stream>>>(
        x, mu, ls, nullptr, nullptr, w, buf0, M0, 512, 0);
    spn_level<128, false><<<dim3(256, 2), dim3(512), shA, stream>>>(
        nullptr, nullptr, nullptr, buf0, M0, w, buf1, M1, 256, 512);
    spn_level<128, false><<<dim3(128, 2), dim3(512), shA, stream>>>(
        nullptr, nullptr, nullptr, buf1, M1, w, buf0, M0, 128, 768);
    spn_level<128, false><<<dim3(64, 2), dim3(512), shA, stream>>>(
        nullptr, nullptr, nullptr, buf0, M0, w, buf1, M1, 64, 896);
    spn_level<32, false><<<dim3(32, 8), dim3(512), shA, stream>>>(
        nullptr, nullptr, nullptr, buf1, M1, w, buf0, M0, 32, 960);
    spn_tail<<<dim3(64), dim3(512), 0, stream>>>(buf0, M0, planes, out);
}